// Round 7
// baseline (54.932 us; speedup 1.0000x reference)
//
#include <hip/hip_runtime.h>

#define Bn 16
#define Qn 128
#define Kn 128
#define Dn 512
#define Hn 512
#define NEGV (-3.0e38f)
// 2*log2(e): exp2(PSCALE*x) == e^{2x}
#define PSCALE 2.8853900817779268f

typedef short s16x8 __attribute__((ext_vector_type(8)));
typedef float f32x4 __attribute__((ext_vector_type(4)));

__device__ __forceinline__ float exp2_hw(float x) {
  float r;
  asm("v_exp_f32 %0, %1" : "=v"(r) : "v"(x));
  return r;
}
__device__ __forceinline__ float rcp_hw(float x) { return __builtin_amdgcn_rcpf(x); }
__device__ __forceinline__ unsigned short f2bf(float f) {   // RNE f32->bf16
  unsigned int u = __float_as_uint(f);
  u += 0x7fff + ((u >> 16) & 1);
  return (unsigned short)(u >> 16);
}

// ---------- K1: convert inputs to bf16 (A rows, W transposed, V transposed) ----------
__global__ __launch_bounds__(256) void convert_kernel(
    const float* __restrict__ queries, const float* __restrict__ keys,
    const float* __restrict__ Wq, const float* __restrict__ Wk,
    const float* __restrict__ values,
    unsigned short* __restrict__ Abf, unsigned short* __restrict__ Wt,
    unsigned short* __restrict__ Vt)
{
  const int bid = blockIdx.x, t = threadIdx.x;
  if (bid < 512) {
    const int gid = bid * 256 + t;
    const size_t base = (size_t)gid * 16;
    const float* src = (base < 1048576) ? (queries + base) : (keys + (base - 1048576));
    unsigned short o[16];
    #pragma unroll
    for (int j = 0; j < 4; ++j) {
      float4 v = *(const float4*)(src + j * 4);
      o[j * 4 + 0] = f2bf(v.x); o[j * 4 + 1] = f2bf(v.y);
      o[j * 4 + 2] = f2bf(v.z); o[j * 4 + 3] = f2bf(v.w);
    }
    #pragma unroll
    for (int j = 0; j < 4; ++j)
      *(ushort4*)(Abf + base + j * 4) = *(ushort4*)&o[j * 4];
  } else if (bid < 640) {
    const int tid = (bid - 512) * 256 + t;
    const int n = tid & 511, rest = tid >> 9;
    const int sel = rest >> 5, k16 = rest & 31;
    const float* W = sel ? Wk : Wq;
    unsigned short o[16];
    #pragma unroll
    for (int i = 0; i < 16; ++i)
      o[i] = f2bf(W[(size_t)(k16 * 16 + i) * Hn + n]);
    unsigned short* dst = Wt + (size_t)sel * 262144 + (size_t)n * 512 + k16 * 16;
    #pragma unroll
    for (int j = 0; j < 4; ++j) *(ushort4*)(dst + j * 4) = *(ushort4*)&o[j * 4];
  } else {
    const int tid = (bid - 640) * 256 + t;
    const int d = tid & 511, rest = tid >> 9;
    const int b = rest >> 2, k32 = rest & 3;
    unsigned short o[32];
    #pragma unroll
    for (int i = 0; i < 32; ++i)
      o[i] = f2bf(values[((size_t)(b * Kn + k32 * 32 + i)) * Dn + d]);
    unsigned short* dst = Vt + (size_t)b * 65536 + (size_t)d * 128 + k32 * 32;
    #pragma unroll
    for (int j = 0; j < 8; ++j) *(ushort4*)(dst + j * 4) = *(ushort4*)&o[j * 4];
  }
}

// ---------- K2: projections via bf16 MFMA ----------
// q rows -> QW[q_glob][512 h][{WF=-2*wv*e^{-2q}, F=e^{-2q}}] f32
// k rows -> Ekq[b][512 h][128 k] = e^{2k} f32 (k-contiguous), via LDS transpose
__global__ __launch_bounds__(256) void proj_mfma(
    const unsigned short* __restrict__ Abf, const unsigned short* __restrict__ Wt,
    const float* __restrict__ wv,
    float* __restrict__ QW, float* __restrict__ Ekq)
{
  __shared__ unsigned short Al[128][72];
  __shared__ unsigned short Bl[64][72];
  __shared__ float Tep[64][132];           // epilogue transpose tile (k-proj)
  const int t = threadIdx.x, w = t >> 6, l = t & 63;
  const int wm = w >> 1, wn = w & 1;
  const int rowTile = blockIdx.x;          // 0..31
  const int n0 = blockIdx.y * 64;
  const int R0 = rowTile * 128;
  const bool isQ = rowTile < 16;
  const unsigned short* Wsel = Wt + (isQ ? 0 : 262144);

  f32x4 acc[4][2];
  #pragma unroll
  for (int m = 0; m < 4; ++m)
    #pragma unroll
    for (int n = 0; n < 2; ++n) acc[m][n] = (f32x4)0.f;

  const int lr = l & 15, lk = l >> 4;

  for (int k0 = 0; k0 < Hn; k0 += 64) {
    ushort4 ar[4][2], br[2][2];
    #pragma unroll
    for (int i = 0; i < 4; ++i) {
      int g = t + 256 * i, r = g >> 3, c = g & 7;
      const unsigned short* p = Abf + (size_t)(R0 + r) * Hn + k0 + c * 8;
      ar[i][0] = *(const ushort4*)p; ar[i][1] = *(const ushort4*)(p + 4);
    }
    #pragma unroll
    for (int i = 0; i < 2; ++i) {
      int g = t + 256 * i, r = g >> 3, c = g & 7;
      const unsigned short* p = Wsel + (size_t)(n0 + r) * Hn + k0 + c * 8;
      br[i][0] = *(const ushort4*)p; br[i][1] = *(const ushort4*)(p + 4);
    }
    __syncthreads();
    #pragma unroll
    for (int i = 0; i < 4; ++i) {
      int g = t + 256 * i, r = g >> 3, c = g & 7;
      *(ushort4*)&Al[r][c * 8] = ar[i][0]; *(ushort4*)&Al[r][c * 8 + 4] = ar[i][1];
    }
    #pragma unroll
    for (int i = 0; i < 2; ++i) {
      int g = t + 256 * i, r = g >> 3, c = g & 7;
      *(ushort4*)&Bl[r][c * 8] = br[i][0]; *(ushort4*)&Bl[r][c * 8 + 4] = br[i][1];
    }
    __syncthreads();
    #pragma unroll
    for (int ks = 0; ks < 2; ++ks) {
      s16x8 af[4], bf_[2];
      #pragma unroll
      for (int m = 0; m < 4; ++m)
        af[m] = *(const s16x8*)&Al[wm * 64 + m * 16 + lr][ks * 32 + lk * 8];
      #pragma unroll
      for (int n = 0; n < 2; ++n)
        bf_[n] = *(const s16x8*)&Bl[wn * 32 + n * 16 + lr][ks * 32 + lk * 8];
      #pragma unroll
      for (int m = 0; m < 4; ++m)
        #pragma unroll
        for (int n = 0; n < 2; ++n)
          acc[m][n] = __builtin_amdgcn_mfma_f32_16x16x32_bf16(af[m], bf_[n], acc[m][n], 0, 0, 0);
    }
    __syncthreads();
  }

  if (isQ) {
    #pragma unroll
    for (int m = 0; m < 4; ++m)
      #pragma unroll
      for (int n = 0; n < 2; ++n)
        #pragma unroll
        for (int r = 0; r < 4; ++r) {
          int row = R0 + wm * 64 + m * 16 + lk * 4 + r;
          int col = n0 + wn * 32 + n * 16 + lr;      // h
          float a = acc[m][n][r];
          float F  = exp2_hw(-PSCALE * a);           // e^{-2q}
          float WF = -2.f * wv[col] * F;
          float2 o = {WF, F};
          *(float2*)(QW + ((size_t)row * Hn + col) * 2) = o;
        }
  } else {
    const int bb = rowTile - 16;
    #pragma unroll
    for (int m = 0; m < 4; ++m)
      #pragma unroll
      for (int n = 0; n < 2; ++n)
        #pragma unroll
        for (int r = 0; r < 4; ++r) {
          int row_l = wm * 64 + m * 16 + lk * 4 + r;   // k
          int col_l = wn * 32 + n * 16 + lr;           // h (local)
          Tep[col_l][row_l] = exp2_hw(PSCALE * acc[m][n][r]);
        }
    __syncthreads();
    const int hl = t >> 2, kq = (t & 3) * 32;
    float* dst = Ekq + (size_t)bb * 65536 + (size_t)(n0 + hl) * 128 + kq;
    #pragma unroll
    for (int j = 0; j < 8; ++j)
      *(float4*)(dst + j * 4) = *(const float4*)&Tep[hl][kq + j * 4];
  }
}

// ---------- K3: score partials, no LDS, no barriers ----------
// Block = 256 thr = 4 waves. id -> (g = b*8+hs, qt). 1024 blocks (4 waves/SIMD).
// Wave covers 4 q x 128 k; lane: 1 q (l>>4), 8 k ((l&15)*8); h-chunk of 64.
// term(q,k,h) = WF[q,h] / (F[q,h] + Ek[k,h]); 2 h share one rcp. Prefetch depth 2.
struct ScoreSet { float4 e0a, e0b, e1a, e1b, qv; };

__device__ __forceinline__ void load_set(ScoreSet& s, const float* ek,
                                         const float* qwp, int hb) {
  const float* ep = ek + (size_t)(2 * hb) * 128;
  s.e0a = *(const float4*)(ep);
  s.e0b = *(const float4*)(ep + 4);
  s.e1a = *(const float4*)(ep + 128);
  s.e1b = *(const float4*)(ep + 132);
  s.qv  = *(const float4*)(qwp + 4 * hb);
}

__device__ __forceinline__ void compute_set(const ScoreSet& s, float acc[8]) {
  const float WF0 = s.qv.x, F0 = s.qv.y, WF1 = s.qv.z, F1 = s.qv.w;
  float d0, d1, num;
  d0 = F0 + s.e0a.x; d1 = F1 + s.e1a.x;
  num = __builtin_fmaf(WF0, d1, WF1 * d0);
  acc[0] = __builtin_fmaf(num, rcp_hw(d0 * d1), acc[0]);
  d0 = F0 + s.e0a.y; d1 = F1 + s.e1a.y;
  num = __builtin_fmaf(WF0, d1, WF1 * d0);
  acc[1] = __builtin_fmaf(num, rcp_hw(d0 * d1), acc[1]);
  d0 = F0 + s.e0a.z; d1 = F1 + s.e1a.z;
  num = __builtin_fmaf(WF0, d1, WF1 * d0);
  acc[2] = __builtin_fmaf(num, rcp_hw(d0 * d1), acc[2]);
  d0 = F0 + s.e0a.w; d1 = F1 + s.e1a.w;
  num = __builtin_fmaf(WF0, d1, WF1 * d0);
  acc[3] = __builtin_fmaf(num, rcp_hw(d0 * d1), acc[3]);
  d0 = F0 + s.e0b.x; d1 = F1 + s.e1b.x;
  num = __builtin_fmaf(WF0, d1, WF1 * d0);
  acc[4] = __builtin_fmaf(num, rcp_hw(d0 * d1), acc[4]);
  d0 = F0 + s.e0b.y; d1 = F1 + s.e1b.y;
  num = __builtin_fmaf(WF0, d1, WF1 * d0);
  acc[5] = __builtin_fmaf(num, rcp_hw(d0 * d1), acc[5]);
  d0 = F0 + s.e0b.z; d1 = F1 + s.e1b.z;
  num = __builtin_fmaf(WF0, d1, WF1 * d0);
  acc[6] = __builtin_fmaf(num, rcp_hw(d0 * d1), acc[6]);
  d0 = F0 + s.e0b.w; d1 = F1 + s.e1b.w;
  num = __builtin_fmaf(WF0, d1, WF1 * d0);
  acc[7] = __builtin_fmaf(num, rcp_hw(d0 * d1), acc[7]);
}

__global__ __launch_bounds__(256) void score_kernel(
    const float* __restrict__ QW, const float* __restrict__ Ekq,
    float* __restrict__ Sp)
{
  const int id = blockIdx.x;
  const int g = id & 127, qt = id >> 7;    // siblings stride 128 -> same XCD
  const int b = g >> 3, hs = g & 7;
  const int t = threadIdx.x, w = t >> 6, l = t & 63;
  const int q  = qt * 16 + w * 4 + (l >> 4);
  const int k0 = (l & 15) * 8;
  const int h0 = hs * 64;

  const float* ek  = Ekq + (size_t)b * 65536 + (size_t)h0 * 128 + k0;
  const float* qwp = QW + ((size_t)(b * Qn + q) * Hn + h0) * 2;

  float acc[8];
  #pragma unroll
  for (int j = 0; j < 8; ++j) acc[j] = 0.f;

  ScoreSet sA, sB;
  load_set(sA, ek, qwp, 0);
  load_set(sB, ek, qwp, 1);
  #pragma unroll 4
  for (int hb = 0; hb < 32; hb += 2) {
    compute_set(sA, acc);
    if (hb + 2 < 32) load_set(sA, ek, qwp, hb + 2);
    compute_set(sB, acc);
    if (hb + 3 < 32) load_set(sB, ek, qwp, hb + 3);
  }

  float4 o0 = {acc[0], acc[1], acc[2], acc[3]};
  float4 o1 = {acc[4], acc[5], acc[6], acc[7]};
  size_t sb = (((size_t)hs * Bn + b) * Qn + q) * Kn + k0;
  *(float4*)(Sp + sb) = o0;
  *(float4*)(Sp + sb + 4) = o1;
}

// ---------- K4: sum 8 h-partials + masked softmax -> At bf16 ----------
__global__ __launch_bounds__(512) void softmax_kernel(
    const float* __restrict__ Sp, const int* __restrict__ valid_lens,
    unsigned short* __restrict__ At)
{
  const int t = threadIdx.x;
  const int b = blockIdx.y;
  const int q = blockIdx.x * 16 + (t >> 5);
  const int k0 = (t & 31) * 4;
  const size_t base = ((size_t)b * Qn + q) * Kn + k0;

  float s[4] = {0.f, 0.f, 0.f, 0.f};
  #pragma unroll
  for (int p = 0; p < 8; ++p) {
    float4 sv = *(const float4*)(Sp + base + (size_t)p * 262144);
    s[0] += sv.x; s[1] += sv.y; s[2] += sv.z; s[3] += sv.w;
  }

  const int vlen = valid_lens[b];
  bool ok[4];
  float m = NEGV;
  #pragma unroll
  for (int j = 0; j < 4; ++j) {
    ok[j] = (k0 + j) < vlen;
    if (ok[j]) m = fmaxf(m, s[j]);
  }
  #pragma unroll
  for (int xm = 16; xm >= 1; xm >>= 1) m = fmaxf(m, __shfl_xor(m, xm, 32));
  float e[4], sum = 0.f;
  #pragma unroll
  for (int j = 0; j < 4; ++j) {
    e[j] = ok[j] ? exp2_hw((s[j] - m) * 1.44269504f) : 0.f;
    sum += e[j];
  }
  #pragma unroll
  for (int xm = 16; xm >= 1; xm >>= 1) sum += __shfl_xor(sum, xm, 32);
  float inv = rcp_hw(sum);
  ushort4 o = {f2bf(e[0] * inv), f2bf(e[1] * inv), f2bf(e[2] * inv), f2bf(e[3] * inv)};
  *(ushort4*)(At + base) = o;
}

// ---------- K5: out = At @ V via bf16 MFMA ----------
__global__ __launch_bounds__(256) void av_mfma(
    const unsigned short* __restrict__ At, const unsigned short* __restrict__ Vt,
    float* __restrict__ out)
{
  __shared__ unsigned short AtL[128][72];
  __shared__ unsigned short VL[128][72];
  const int t = threadIdx.x, w = t >> 6, l = t & 63;
  const int wm = w >> 1, wn = w & 1;
  const int dt = blockIdx.x;
  const int b = blockIdx.y;
  const int lr = l & 15, lk = l >> 4;

  f32x4 acc[4][4];
  #pragma unroll
  for (int m = 0; m < 4; ++m)
    #pragma unroll
    for (int n = 0; n < 4; ++n) acc[m][n] = (f32x4)0.f;

  const unsigned short* Atb = At + (size_t)b * Qn * Kn;
  const unsigned short* Vtb = Vt + (size_t)b * 65536 + (size_t)dt * 128 * Kn;

  for (int k0 = 0; k0 < Kn; k0 += 64) {
    ushort4 ar[4][2], vr[4][2];
    #pragma unroll
    for (int i = 0; i < 4; ++i) {
      int g = t + 256 * i, r = g >> 3, c = g & 7;
      const unsigned short* p = Atb + (size_t)r * Kn + k0 + c * 8;
      ar[i][0] = *(const ushort4*)p; ar[i][1] = *(const ushort4*)(p + 4);
      const unsigned short* pv = Vtb + (size_t)r * Kn + k0 + c * 8;
      vr[i][0] = *(const ushort4*)pv; vr[i][1] = *(const ushort4*)(pv + 4);
    }
    __syncthreads();
    #pragma unroll
    for (int i = 0; i < 4; ++i) {
      int g = t + 256 * i, r = g >> 3, c = g & 7;
      *(ushort4*)&AtL[r][c * 8] = ar[i][0]; *(ushort4*)&AtL[r][c * 8 + 4] = ar[i][1];
      *(ushort4*)&VL[r][c * 8] = vr[i][0];  *(ushort4*)&VL[r][c * 8 + 4] = vr[i][1];
    }
    __syncthreads();
    #pragma unroll
    for (int ks = 0; ks < 2; ++ks) {
      s16x8 af[4], bf_[4];
      #pragma unroll
      for (int m = 0; m < 4; ++m)
        af[m] = *(const s16x8*)&AtL[wm * 64 + m * 16 + lr][ks * 32 + lk * 8];
      #pragma unroll
      for (int n = 0; n < 4; ++n)
        bf_[n] = *(const s16x8*)&VL[wn * 64 + n * 16 + lr][ks * 32 + lk * 8];
      #pragma unroll
      for (int m = 0; m < 4; ++m)
        #pragma unroll
        for (int n = 0; n < 4; ++n)
          acc[m][n] = __builtin_amdgcn_mfma_f32_16x16x32_bf16(af[m], bf_[n], acc[m][n], 0, 0, 0);
    }
    __syncthreads();
  }

  #pragma unroll
  for (int m = 0; m < 4; ++m)
    #pragma unroll
    for (int n = 0; n < 4; ++n)
      #pragma unroll
      for (int r = 0; r < 4; ++r) {
        int row = wm * 64 + m * 16 + lk * 4 + r;
        int col = dt * 128 + wn * 64 + n * 16 + lr;
        out[((size_t)(b * Qn) + row) * Dn + col] = acc[m][n][r];
      }
}

extern "C" void kernel_launch(void* const* d_in, const int* in_sizes, int n_in,
                              void* d_out, int out_size, void* d_ws, size_t ws_size,
                              hipStream_t stream) {
  const float* queries    = (const float*)d_in[0];
  const float* keys       = (const float*)d_in[1];
  const float* values     = (const float*)d_in[2];
  const int*   valid_lens = (const int*)d_in[3];
  const float* Wq         = (const float*)d_in[4];
  const float* Wk         = (const float*)d_in[5];
  const float* wv         = (const float*)d_in[6];
  float* out = (float*)d_out;

  unsigned short* Abf = (unsigned short*)d_ws;     // 4096*512 bf16       (4MB)
  unsigned short* Wt  = Abf + 2097152;             // 2*512*512 bf16      (1MB)
  unsigned short* Vt  = Wt + 524288;               // 16*512*128 bf16     (2MB)
  float*          QW  = (float*)(Vt + 1048576);    // 2048*512*2 f32      (8MB)
  float*          Ekq = QW + 2097152;              // 16*512*128 f32      (4MB)
  float*          Sp  = Ekq + 1048576;             // 8*16*128*128 f32    (8MB)
  unsigned short* At  = (unsigned short*)(Sp + 2097152); // 16*128*128    (0.5MB)

  convert_kernel<<<768, 256, 0, stream>>>(queries, keys, Wq, Wk, values, Abf, Wt, Vt);
  proj_mfma<<<dim3(32, 8), 256, 0, stream>>>(Abf, Wt, wv, QW, Ekq);
  score_kernel<<<1024, 256, 0, stream>>>(QW, Ekq, Sp);
  softmax_kernel<<<dim3(8, 16), 512, 0, stream>>>(Sp, valid_lens, At);
  av_mfma<<<dim3(4, 16), 256, 0, stream>>>(At, Vt, out);
}

// Round 8
// 51.786 us; speedup vs baseline: 1.0607x; 1.0607x over previous
//
#include <hip/hip_runtime.h>

#define Bn 16
#define Qn 128
#define Kn 128
#define Dn 512
#define Hn 512
#define NEGV (-3.0e38f)
// 2*log2(e): exp2(PSCALE*x) == e^{2x}
#define PSCALE 2.8853900817779268f

typedef short s16x8 __attribute__((ext_vector_type(8)));
typedef float f32x4 __attribute__((ext_vector_type(4)));

__device__ __forceinline__ float exp2_hw(float x) {
  float r;
  asm("v_exp_f32 %0, %1" : "=v"(r) : "v"(x));
  return r;
}
__device__ __forceinline__ float rcp_hw(float x) { return __builtin_amdgcn_rcpf(x); }
__device__ __forceinline__ unsigned short f2bf(float f) {   // RNE f32->bf16
  unsigned int u = __float_as_uint(f);
  u += 0x7fff + ((u >> 16) & 1);
  return (unsigned short)(u >> 16);
}

// ---------- K1: W transpose + bf16: Wt[2][512 n][512 k] ----------
__global__ __launch_bounds__(256) void convert_w(
    const float* __restrict__ Wq, const float* __restrict__ Wk,
    unsigned short* __restrict__ Wt)
{
  const int tid = blockIdx.x * 256 + threadIdx.x;     // 0..32767
  const int n = tid & 511, rest = tid >> 9;           // rest 0..63
  const int sel = rest >> 5, k16 = rest & 31;
  const float* W = sel ? Wk : Wq;
  unsigned short o[16];
  #pragma unroll
  for (int i = 0; i < 16; ++i)
    o[i] = f2bf(W[(size_t)(k16 * 16 + i) * Hn + n]);
  unsigned short* dst = Wt + (size_t)sel * 262144 + (size_t)n * 512 + k16 * 16;
  #pragma unroll
  for (int j = 0; j < 4; ++j) *(ushort4*)(dst + j * 4) = *(ushort4*)&o[j * 4];
}

// ---------- K2: projections via bf16 MFMA (A read f32 + converted inline) ----------
// q rows -> QW[q_glob][512 h][{WF=-2*wv*e^{-2q}, F=e^{-2q}}] f32
// k rows -> Ekq[b][512 h][128 k] = e^{2k} f32, via LDS transpose epilogue
__global__ __launch_bounds__(256) void proj_mfma(
    const float* __restrict__ queries, const float* __restrict__ keys,
    const unsigned short* __restrict__ Wt, const float* __restrict__ wv,
    float* __restrict__ QW, float* __restrict__ Ekq)
{
  __shared__ unsigned short Al[128][72];
  __shared__ unsigned short Bl[64][72];
  __shared__ float Tep[64][132];           // epilogue transpose tile (k-proj)
  const int t = threadIdx.x, w = t >> 6, l = t & 63;
  const int wm = w >> 1, wn = w & 1;
  const int rowTile = blockIdx.x;          // 0..31
  const int n0 = blockIdx.y * 64;
  const int R0 = rowTile * 128;
  const bool isQ = rowTile < 16;
  const float* Asrc = isQ ? queries : keys;
  const int rowBase = isQ ? R0 : (R0 - 2048);
  const unsigned short* Wsel = Wt + (isQ ? 0 : 262144);

  f32x4 acc[4][2];
  #pragma unroll
  for (int m = 0; m < 4; ++m)
    #pragma unroll
    for (int n = 0; n < 2; ++n) acc[m][n] = (f32x4)0.f;

  const int lr = l & 15, lk = l >> 4;

  for (int k0 = 0; k0 < Hn; k0 += 64) {
    float4 afr[8];
    ushort4 br[2][2];
    #pragma unroll
    for (int i = 0; i < 8; ++i) {
      int g = t + 256 * i, r = g >> 4, c4 = g & 15;
      afr[i] = *(const float4*)(Asrc + (size_t)(rowBase + r) * Dn + k0 + c4 * 4);
    }
    #pragma unroll
    for (int i = 0; i < 2; ++i) {
      int g = t + 256 * i, r = g >> 3, c = g & 7;
      const unsigned short* p = Wsel + (size_t)(n0 + r) * Hn + k0 + c * 8;
      br[i][0] = *(const ushort4*)p; br[i][1] = *(const ushort4*)(p + 4);
    }
    __syncthreads();
    #pragma unroll
    for (int i = 0; i < 8; ++i) {
      int g = t + 256 * i, r = g >> 4, c4 = g & 15;
      ushort4 o = {f2bf(afr[i].x), f2bf(afr[i].y), f2bf(afr[i].z), f2bf(afr[i].w)};
      *(ushort4*)&Al[r][c4 * 4] = o;
    }
    #pragma unroll
    for (int i = 0; i < 2; ++i) {
      int g = t + 256 * i, r = g >> 3, c = g & 7;
      *(ushort4*)&Bl[r][c * 8] = br[i][0]; *(ushort4*)&Bl[r][c * 8 + 4] = br[i][1];
    }
    __syncthreads();
    #pragma unroll
    for (int ks = 0; ks < 2; ++ks) {
      s16x8 af[4], bf_[2];
      #pragma unroll
      for (int m = 0; m < 4; ++m)
        af[m] = *(const s16x8*)&Al[wm * 64 + m * 16 + lr][ks * 32 + lk * 8];
      #pragma unroll
      for (int n = 0; n < 2; ++n)
        bf_[n] = *(const s16x8*)&Bl[wn * 32 + n * 16 + lr][ks * 32 + lk * 8];
      #pragma unroll
      for (int m = 0; m < 4; ++m)
        #pragma unroll
        for (int n = 0; n < 2; ++n)
          acc[m][n] = __builtin_amdgcn_mfma_f32_16x16x32_bf16(af[m], bf_[n], acc[m][n], 0, 0, 0);
    }
    __syncthreads();
  }

  if (isQ) {
    #pragma unroll
    for (int m = 0; m < 4; ++m)
      #pragma unroll
      for (int n = 0; n < 2; ++n)
        #pragma unroll
        for (int r = 0; r < 4; ++r) {
          int row = R0 + wm * 64 + m * 16 + lk * 4 + r;
          int col = n0 + wn * 32 + n * 16 + lr;      // h
          float a = acc[m][n][r];
          float F  = exp2_hw(-PSCALE * a);           // e^{-2q}
          float WF = -2.f * wv[col] * F;
          float2 o = {WF, F};
          *(float2*)(QW + ((size_t)row * Hn + col) * 2) = o;
        }
  } else {
    const int bb = rowTile - 16;
    #pragma unroll
    for (int m = 0; m < 4; ++m)
      #pragma unroll
      for (int n = 0; n < 2; ++n)
        #pragma unroll
        for (int r = 0; r < 4; ++r) {
          int row_l = wm * 64 + m * 16 + lk * 4 + r;   // k
          int col_l = wn * 32 + n * 16 + lr;           // h (local)
          Tep[col_l][row_l] = exp2_hw(PSCALE * acc[m][n][r]);
        }
    __syncthreads();
    const int hl = t >> 2, kq = (t & 3) * 32;
    float* dst = Ekq + (size_t)bb * 65536 + (size_t)(n0 + hl) * 128 + kq;
    #pragma unroll
    for (int j = 0; j < 8; ++j)
      *(float4*)(dst + j * 4) = *(const float4*)&Tep[hl][kq + j * 4];
  }
}

// ---------- K3: score partials — LDS-staged, zero in-loop VMEM ----------
// Block = 256 thr (4 waves), owns (b, hs 64h-chunk, 16 q, all 128 k).
// Stage EkL[64h][128k] (32KB) + QWL[16q][64h][2] (8KB) once; 32 compute iters.
// Lane: q_l = w*4 + (l>>4); k = {ka..ka+3, 64+ka..+3}, ka = (l&15)*4.
// term(q,k,h) = WF[q,h] / (F[q,h] + Ek[k,h]); 2 h share one rcp.
__global__ __launch_bounds__(256) void score_kernel(
    const float* __restrict__ QW, const float* __restrict__ Ekq,
    float* __restrict__ Sp)
{
  __shared__ float EkL[8192];              // [64 h][128 k] = 32KB
  __shared__ float QWL[2048];              // [16 q][64 h][2] = 8KB
  const int id = blockIdx.x;
  const int g = id & 127, qt = id >> 7;    // (b,hs)-siblings stride 128 -> same XCD
  const int b = g >> 3, hs = g & 7;
  const int t = threadIdx.x, w = t >> 6, l = t & 63;
  const int q_l = w * 4 + (l >> 4);
  const int ka = (l & 15) * 4;

  // ---- stage ----
  {
    const float4* esrc = (const float4*)(Ekq + (size_t)b * 65536 + (size_t)hs * 8192);
    float4* edst = (float4*)EkL;
    #pragma unroll
    for (int i = 0; i < 8; ++i) edst[t + 256 * i] = esrc[t + 256 * i];
    const float4* qsrc = (const float4*)QW;
    float4* qdst = (float4*)QWL;
    #pragma unroll
    for (int i = 0; i < 2; ++i) {
      int idx = t + 256 * i;
      int qrow = idx >> 5, rest = idx & 31;
      qdst[idx] = qsrc[(size_t)(b * Qn + qt * 16 + qrow) * 256 + hs * 32 + rest];
    }
  }
  __syncthreads();

  float acc[8];
  #pragma unroll
  for (int j = 0; j < 8; ++j) acc[j] = 0.f;

  #pragma unroll 4
  for (int hb = 0; hb < 32; ++hb) {        // 2 h per iter
    const float* ekp = EkL + hb * 256;
    float4 ea0 = *(const float4*)(ekp + ka);          // h2,   k=ka..
    float4 ea1 = *(const float4*)(ekp + 64 + ka);     // h2,   k=64+ka..
    float4 eb0 = *(const float4*)(ekp + 128 + ka);    // h2+1, k=ka..
    float4 eb1 = *(const float4*)(ekp + 192 + ka);    // h2+1, k=64+ka..
    float4 qv  = *(const float4*)(QWL + q_l * 128 + hb * 4);  // {WF0,F0,WF1,F1}
    const float WF0 = qv.x, F0 = qv.y, WF1 = qv.z, F1 = qv.w;
    float d0, d1, num;
    d0 = F0 + ea0.x; d1 = F1 + eb0.x;
    num = __builtin_fmaf(WF0, d1, WF1 * d0);
    acc[0] = __builtin_fmaf(num, rcp_hw(d0 * d1), acc[0]);
    d0 = F0 + ea0.y; d1 = F1 + eb0.y;
    num = __builtin_fmaf(WF0, d1, WF1 * d0);
    acc[1] = __builtin_fmaf(num, rcp_hw(d0 * d1), acc[1]);
    d0 = F0 + ea0.z; d1 = F1 + eb0.z;
    num = __builtin_fmaf(WF0, d1, WF1 * d0);
    acc[2] = __builtin_fmaf(num, rcp_hw(d0 * d1), acc[2]);
    d0 = F0 + ea0.w; d1 = F1 + eb0.w;
    num = __builtin_fmaf(WF0, d1, WF1 * d0);
    acc[3] = __builtin_fmaf(num, rcp_hw(d0 * d1), acc[3]);
    d0 = F0 + ea1.x; d1 = F1 + eb1.x;
    num = __builtin_fmaf(WF0, d1, WF1 * d0);
    acc[4] = __builtin_fmaf(num, rcp_hw(d0 * d1), acc[4]);
    d0 = F0 + ea1.y; d1 = F1 + eb1.y;
    num = __builtin_fmaf(WF0, d1, WF1 * d0);
    acc[5] = __builtin_fmaf(num, rcp_hw(d0 * d1), acc[5]);
    d0 = F0 + ea1.z; d1 = F1 + eb1.z;
    num = __builtin_fmaf(WF0, d1, WF1 * d0);
    acc[6] = __builtin_fmaf(num, rcp_hw(d0 * d1), acc[6]);
    d0 = F0 + ea1.w; d1 = F1 + eb1.w;
    num = __builtin_fmaf(WF0, d1, WF1 * d0);
    acc[7] = __builtin_fmaf(num, rcp_hw(d0 * d1), acc[7]);
  }

  const int q = qt * 16 + q_l;
  float4 o0 = {acc[0], acc[1], acc[2], acc[3]};
  float4 o1 = {acc[4], acc[5], acc[6], acc[7]};
  size_t sb = (((size_t)hs * Bn + b) * Qn + q) * Kn;
  *(float4*)(Sp + sb + ka) = o0;
  *(float4*)(Sp + sb + 64 + ka) = o1;
}

// ---------- K4: sum 8 h-partials + masked softmax -> At bf16 ----------
__global__ __launch_bounds__(512) void softmax_kernel(
    const float* __restrict__ Sp, const int* __restrict__ valid_lens,
    unsigned short* __restrict__ At)
{
  const int t = threadIdx.x;
  const int b = blockIdx.y;
  const int q = blockIdx.x * 16 + (t >> 5);
  const int k0 = (t & 31) * 4;
  const size_t base = ((size_t)b * Qn + q) * Kn + k0;

  float s[4] = {0.f, 0.f, 0.f, 0.f};
  #pragma unroll
  for (int p = 0; p < 8; ++p) {
    float4 sv = *(const float4*)(Sp + base + (size_t)p * 262144);
    s[0] += sv.x; s[1] += sv.y; s[2] += sv.z; s[3] += sv.w;
  }

  const int vlen = valid_lens[b];
  bool ok[4];
  float m = NEGV;
  #pragma unroll
  for (int j = 0; j < 4; ++j) {
    ok[j] = (k0 + j) < vlen;
    if (ok[j]) m = fmaxf(m, s[j]);
  }
  #pragma unroll
  for (int xm = 16; xm >= 1; xm >>= 1) m = fmaxf(m, __shfl_xor(m, xm, 32));
  float e[4], sum = 0.f;
  #pragma unroll
  for (int j = 0; j < 4; ++j) {
    e[j] = ok[j] ? exp2_hw((s[j] - m) * 1.44269504f) : 0.f;
    sum += e[j];
  }
  #pragma unroll
  for (int xm = 16; xm >= 1; xm >>= 1) sum += __shfl_xor(sum, xm, 32);
  float inv = rcp_hw(sum);
  ushort4 o = {f2bf(e[0] * inv), f2bf(e[1] * inv), f2bf(e[2] * inv), f2bf(e[3] * inv)};
  *(ushort4*)(At + base) = o;
}

// ---------- K5: out = At @ V via bf16 MFMA (V f32 read + LDS transpose) ----------
__global__ __launch_bounds__(256) void av_mfma(
    const unsigned short* __restrict__ At, const float* __restrict__ values,
    float* __restrict__ out)
{
  __shared__ unsigned short AtL[128][72];
  __shared__ unsigned short VL[128][72];
  const int t = threadIdx.x, w = t >> 6, l = t & 63;
  const int wm = w >> 1, wn = w & 1;
  const int dt = blockIdx.x;               // 0..3 (d tile of 128)
  const int b = blockIdx.y;
  const int lr = l & 15, lk = l >> 4;

  f32x4 acc[4][4];
  #pragma unroll
  for (int m = 0; m < 4; ++m)
    #pragma unroll
    for (int n = 0; n < 4; ++n) acc[m][n] = (f32x4)0.f;

  const unsigned short* Atb = At + (size_t)b * Qn * Kn;

  for (int k0 = 0; k0 < Kn; k0 += 64) {
    ushort4 ar[4][2];
    float4 vv[8];
    #pragma unroll
    for (int i = 0; i < 4; ++i) {
      int g = t + 256 * i, r = g >> 3, c = g & 7;
      const unsigned short* p = Atb + (size_t)r * Kn + k0 + c * 8;
      ar[i][0] = *(const ushort4*)p; ar[i][1] = *(const ushort4*)(p + 4);
    }
    #pragma unroll
    for (int j = 0; j < 8; ++j) {
      int idx = t + 256 * j, k_l = idx >> 5, d4 = idx & 31;
      vv[j] = *(const float4*)(values + ((size_t)(b * Kn) + k0 + k_l) * Dn + dt * 128 + d4 * 4);
    }
    __syncthreads();
    #pragma unroll
    for (int i = 0; i < 4; ++i) {
      int g = t + 256 * i, r = g >> 3, c = g & 7;
      *(ushort4*)&AtL[r][c * 8] = ar[i][0]; *(ushort4*)&AtL[r][c * 8 + 4] = ar[i][1];
    }
    #pragma unroll
    for (int j = 0; j < 8; ++j) {
      int idx = t + 256 * j, k_l = idx >> 5, d4 = idx & 31;
      VL[d4 * 4 + 0][k_l] = f2bf(vv[j].x);
      VL[d4 * 4 + 1][k_l] = f2bf(vv[j].y);
      VL[d4 * 4 + 2][k_l] = f2bf(vv[j].z);
      VL[d4 * 4 + 3][k_l] = f2bf(vv[j].w);
    }
    __syncthreads();
    #pragma unroll
    for (int ks = 0; ks < 2; ++ks) {
      s16x8 af[4], bf_[4];
      #pragma unroll
      for (int m = 0; m < 4; ++m)
        af[m] = *(const s16x8*)&AtL[wm * 64 + m * 16 + lr][ks * 32 + lk * 8];
      #pragma unroll
      for (int n = 0; n < 4; ++n)
        bf_[n] = *(const s16x8*)&VL[wn * 64 + n * 16 + lr][ks * 32 + lk * 8];
      #pragma unroll
      for (int m = 0; m < 4; ++m)
        #pragma unroll
        for (int n = 0; n < 4; ++n)
          acc[m][n] = __builtin_amdgcn_mfma_f32_16x16x32_bf16(af[m], bf_[n], acc[m][n], 0, 0, 0);
    }
    __syncthreads();
  }

  #pragma unroll
  for (int m = 0; m < 4; ++m)
    #pragma unroll
    for (int n = 0; n < 4; ++n)
      #pragma unroll
      for (int r = 0; r < 4; ++r) {
        int row = wm * 64 + m * 16 + lk * 4 + r;
        int col = dt * 128 + wn * 64 + n * 16 + lr;
        out[((size_t)(b * Qn) + row) * Dn + col] = acc[m][n][r];
      }
}

extern "C" void kernel_launch(void* const* d_in, const int* in_sizes, int n_in,
                              void* d_out, int out_size, void* d_ws, size_t ws_size,
                              hipStream_t stream) {
  const float* queries    = (const float*)d_in[0];
  const float* keys       = (const float*)d_in[1];
  const float* values     = (const float*)d_in[2];
  const int*   valid_lens = (const int*)d_in[3];
  const float* Wq         = (const float*)d_in[4];
  const float* Wk         = (const float*)d_in[5];
  const float* wv         = (const float*)d_in[6];
  float* out = (float*)d_out;

  unsigned short* Wt  = (unsigned short*)d_ws;     // 2*512*512 bf16      (1MB)
  float*          QW  = (float*)(Wt + 524288);     // 2048*512*2 f32      (8MB)
  float*          Ekq = QW + 2097152;              // 16*512*128 f32      (4MB)
  float*          Sp  = Ekq + 1048576;             // 8*16*128*128 f32    (8MB)
  unsigned short* At  = (unsigned short*)(Sp + 2097152); // 16*128*128    (0.5MB)

  convert_w<<<128, 256, 0, stream>>>(Wq, Wk, Wt);
  proj_mfma<<<dim3(32, 8), 256, 0, stream>>>(queries, keys, Wt, wv, QW, Ekq);
  score_kernel<<<1024, 256, 0, stream>>>(QW, Ekq, Sp);
  softmax_kernel<<<dim3(8, 16), 512, 0, stream>>>(Sp, valid_lens, At);
  av_mfma<<<dim3(4, 16), 256, 0, stream>>>(At, values, out);
}